// Round 14
// baseline (413.742 us; speedup 1.0000x reference)
//
#include <hip/hip_runtime.h>
#include <hip/hip_bf16.h>

#define HID 128
#define CAP 64   // bucket capacity: deg ~ Poisson(16), P(any node >= 64) ~ 1e-14
#define NBK 2048 // scatter blocks in k_prep
#define NWC 192  // weight-convert blocks (covers 3*128*128 = 49152 >= 128*256)

typedef __attribute__((ext_vector_type(8))) short bfrag;   // 8 bf16 = 4 VGPR
typedef __attribute__((ext_vector_type(4))) float f32x4;

static inline size_t align256(size_t x) { return (x + 255) & ~(size_t)255; }

__device__ __forceinline__ unsigned short f2bf(float f) {
  unsigned int x = __float_as_uint(f);
  unsigned int r = x + 0x7fffu + ((x >> 16) & 1u);  // RNE
  return (unsigned short)(r >> 16);
}
__device__ __forceinline__ float bflo(unsigned int u) { return __uint_as_float(u << 16); }
__device__ __forceinline__ float bfhi(unsigned int u) { return __uint_as_float(u & 0xffff0000u); }

// ---------------- prep: XCD-sliced scatter + weight converts + goff + sentinel zero ------
// Register-lean (no LDS, ~4 VGPR in scatter role) so scatter waves keep full occupancy
// for atomic-latency hiding (round-10 lesson: merging with MFMA init throttled it).

__global__ __launch_bounds__(256) void k_prep(const int* __restrict__ src,
                                              const int* __restrict__ dst,
                                              int* __restrict__ cnt,
                                              int* __restrict__ bsrc, int E, int N,
                                              const float* __restrict__ W_comb,
                                              const float* __restrict__ gW1,
                                              const float* __restrict__ gW2,
                                              unsigned short* __restrict__ Wcb,
                                              unsigned short* __restrict__ W1b,
                                              unsigned short* __restrict__ W2b,
                                              const int* __restrict__ batch,
                                              int* __restrict__ goff, int G,
                                              unsigned int* __restrict__ UbZ,
                                              unsigned int* __restrict__ VbZ) {
  const int bid = blockIdx.x;
  const int tid = threadIdx.x;
  if (bid < NBK) {  // ---- XCD-sliced bucket scatter ----
    const int slice = bid & 7;
    const int sidx = bid >> 3;
    const int s_lo = (int)(((long long)slice * N) >> 3);
    const int s_hi = (int)(((long long)(slice + 1) * N) >> 3);
    for (int e = sidx * 256 + tid; e < E; e += (NBK / 8) * 256) {
      int d = dst[e];
      if (d >= s_lo && d < s_hi) {
        int slot = atomicAdd(&cnt[d], 1);
        if (slot < CAP) bsrc[(size_t)d * CAP + slot] = src[e];
      }
    }
  } else if (bid < NBK + NWC) {  // ---- Wc/gW1/gW2 f32->bf16 ----
    int i = (bid - NBK) * 256 + tid;
    if (i < 128 * 256) Wcb[i] = f2bf(W_comb[i]);
    if (i < 3 * 128 * 128) {
      W1b[i] = f2bf(gW1[i]);
      W2b[i] = f2bf(gW2[i]);
    }
  } else {  // ---- goff binary search + sentinel zero rows ----
    int g = (bid - NBK - NWC) * 256 + tid;
    if (g <= G) {
      int lo = 0, hi = N;
      while (lo < hi) {
        int mid = (lo + hi) >> 1;
        if (batch[mid] < g) lo = mid + 1; else hi = mid;
      }
      goff[g] = lo;
    }
    if (bid == NBK + NWC) {
      if (tid >= 64 && tid < 128) UbZ[tid - 64] = 0;
      else if (tid >= 128 && tid < 192) VbZ[tid - 128] = 0;
    }
  }
}

// ---------------- fused init: [emb(z)||pos-proj] -> GEMM Wc(K=256) -> relu -> GEMM W1[0] ----
// Weights pre-converted to bf16 by k_prep (round-11 lesson: in-register f32 convert
// cost 108 VGPR / 19% occupancy / 93us — as much as a whole layer).

__global__ __launch_bounds__(256, 2) void k_init_mm(const int* __restrict__ z,
                                                    const float* __restrict__ pos,
                                                    const float* __restrict__ emb,
                                                    const float* __restrict__ W_pos,
                                                    const float* __restrict__ b_pos,
                                                    const unsigned short* __restrict__ Wcb,
                                                    const float* __restrict__ b_comb,
                                                    const unsigned short* __restrict__ W1n,
                                                    unsigned short* __restrict__ Y, int n) {
  __shared__ unsigned int sE[32 * 128];  // input rows (256 bf16), swizzled
  __shared__ unsigned int sB[32 * 64];   // intermediate x rows (128 bf16), swizzled
  const int t = threadIdx.x;
  const int w = t >> 6, l = t & 63, lr = l & 15, lk = l >> 4;

  bfrag wcf[2][8];
#pragma unroll
  for (int s = 0; s < 2; ++s)
#pragma unroll
    for (int ks = 0; ks < 8; ++ks)
      wcf[s][ks] = *(const bfrag*)(Wcb + (size_t)(32 * w + 16 * s + lr) * 256 + ks * 32 + lk * 8);
  bfrag w1f[2][4];
#pragma unroll
  for (int s = 0; s < 2; ++s)
#pragma unroll
    for (int ks = 0; ks < 4; ++ks)
      w1f[s][ks] = *(const bfrag*)(W1n + (size_t)(32 * w + 16 * s + lr) * HID + ks * 32 + lk * 8);
  const float bias0 = b_comb[32 * w + lr];
  const float bias1 = b_comb[32 * w + 16 + lr];

  const int m0 = blockIdx.x * 32;
  {
    const int r = t >> 3, i = t & 7;
    int node = m0 + r;
    if (node >= n) node = n - 1;
    const int zz = z[node];
    const float p0 = pos[node * 3 + 0], p1 = pos[node * 3 + 1], p2 = pos[node * 3 + 2];
    const int swz = (r & 7) << 2;
#pragma unroll
    for (int k = 0; k < 16; ++k) {
      const int j = i + k * 8;
      float v0, v1;
      if (j < 64) {
        const float2 ev = *(const float2*)&emb[(size_t)zz * 128 + 2 * j];
        v0 = ev.x; v1 = ev.y;
      } else {
        const int f0 = 2 * j - 128;
        v0 = b_pos[f0] + W_pos[f0 * 3] * p0 + W_pos[f0 * 3 + 1] * p1 + W_pos[f0 * 3 + 2] * p2;
        v1 = b_pos[f0 + 1] + W_pos[f0 * 3 + 3] * p0 + W_pos[f0 * 3 + 4] * p1 +
             W_pos[f0 * 3 + 5] * p2;
      }
      sE[r * 128 + (j ^ swz)] = (unsigned int)f2bf(v0) | ((unsigned int)f2bf(v1) << 16);
    }
  }
  __syncthreads();

  f32x4 acc00 = {0.f, 0.f, 0.f, 0.f}, acc01 = acc00, acc10 = acc00, acc11 = acc00;
#pragma unroll
  for (int mt = 0; mt < 2; ++mt) {
    const int row = 16 * mt + lr;
    const int swz = (row & 7) << 2;
#pragma unroll
    for (int ks = 0; ks < 8; ++ks) {
      const bfrag a = *(const bfrag*)&sE[row * 128 + ((ks * 16 + lk * 4) ^ swz)];
      if (mt == 0) {
        acc00 = __builtin_amdgcn_mfma_f32_16x16x32_bf16(a, wcf[0][ks], acc00, 0, 0, 0);
        acc01 = __builtin_amdgcn_mfma_f32_16x16x32_bf16(a, wcf[1][ks], acc01, 0, 0, 0);
      } else {
        acc10 = __builtin_amdgcn_mfma_f32_16x16x32_bf16(a, wcf[0][ks], acc10, 0, 0, 0);
        acc11 = __builtin_amdgcn_mfma_f32_16x16x32_bf16(a, wcf[1][ks], acc11, 0, 0, 0);
      }
    }
  }
  {
    unsigned short* sB16 = (unsigned short*)sB;
#pragma unroll
    for (int mt = 0; mt < 2; ++mt) {
#pragma unroll
      for (int s = 0; s < 2; ++s) {
        const f32x4 a = mt == 0 ? (s == 0 ? acc00 : acc01) : (s == 0 ? acc10 : acc11);
        const float bb = s == 0 ? bias0 : bias1;
        const int col = 32 * w + 16 * s + lr;
#pragma unroll
        for (int r = 0; r < 4; ++r) {
          const int rowL = 16 * mt + 4 * lk + r;
          const int cu = (col >> 1) ^ ((rowL & 7) << 2);
          sB16[rowL * 128 + cu * 2 + (col & 1)] = f2bf(fmaxf(a[r] + bb, 0.f));
        }
      }
    }
  }
  __syncthreads();

  f32x4 u00 = {0.f, 0.f, 0.f, 0.f}, u01 = u00, u10 = u00, u11 = u00;
#pragma unroll
  for (int mt = 0; mt < 2; ++mt) {
    const int row = 16 * mt + lr;
    const int swz = (row & 7) << 2;
#pragma unroll
    for (int ks = 0; ks < 4; ++ks) {
      const bfrag a = *(const bfrag*)&sB[row * 64 + ((ks * 16 + lk * 4) ^ swz)];
      if (mt == 0) {
        u00 = __builtin_amdgcn_mfma_f32_16x16x32_bf16(a, w1f[0][ks], u00, 0, 0, 0);
        u01 = __builtin_amdgcn_mfma_f32_16x16x32_bf16(a, w1f[1][ks], u01, 0, 0, 0);
      } else {
        u10 = __builtin_amdgcn_mfma_f32_16x16x32_bf16(a, w1f[0][ks], u10, 0, 0, 0);
        u11 = __builtin_amdgcn_mfma_f32_16x16x32_bf16(a, w1f[1][ks], u11, 0, 0, 0);
      }
    }
  }
#pragma unroll
  for (int mt = 0; mt < 2; ++mt) {
#pragma unroll
    for (int s = 0; s < 2; ++s) {
      const f32x4 a = mt == 0 ? (s == 0 ? u00 : u01) : (s == 0 ? u10 : u11);
      const int col = 32 * w + 16 * s + lr;
#pragma unroll
      for (int r = 0; r < 4; ++r) {
        const int row = m0 + 16 * mt + 4 * lk + r;
        if (row < n) Y[(size_t)row * HID + col] = f2bf(a[r]);
      }
    }
  }
}

// ---------------- fused layer: gather(u)+b1+relu -> GEMM W2(+b2,relu) -> GEMM W1next --------
// Gather: 16 lanes x 16B cover one 256B row; 4 lane-groups process 4 edges at once.
// 16-edge main step (4 uint4 loads in flight) + 8-edge tail; lane-indices padded to
// sentinel zero row n -> branch-free. launch_bounds(256,4): proven no-spill config
// (round-12 lesson: (256,6) forced spill; round-13 verified 64 VGPR / 25MB WRITE).

template <int LAST>
__global__ __launch_bounds__(256, 4) void k_layer(const unsigned int* __restrict__ U,
                                                  const int* __restrict__ cnt,
                                                  const int* __restrict__ bsrc,
                                                  const float* __restrict__ b1,
                                                  const unsigned short* __restrict__ W2b,
                                                  const float* __restrict__ b2,
                                                  const unsigned short* __restrict__ W1n,
                                                  unsigned short* __restrict__ Y, int n) {
  __shared__ unsigned int sA[32 * 64];  // h rows (gathered, post-relu), swizzled
  __shared__ unsigned int sB[32 * 64];  // x rows (W2 output), swizzled
  const int t = threadIdx.x;
  const int w = t >> 6, l = t & 63, lr = l & 15, lk = l >> 4;
  const int lgrp = lk, lpos = lr;  // gather aliases: group 0..3, position 0..15

  bfrag w2f[2][4];
#pragma unroll
  for (int s = 0; s < 2; ++s)
#pragma unroll
    for (int ks = 0; ks < 4; ++ks)
      w2f[s][ks] = *(const bfrag*)(W2b + (size_t)(32 * w + 16 * s + lr) * HID + ks * 32 + lk * 8);
  bfrag w1f[2][4];
  if (!LAST) {
#pragma unroll
    for (int s = 0; s < 2; ++s)
#pragma unroll
      for (int ks = 0; ks < 4; ++ks)
        w1f[s][ks] = *(const bfrag*)(W1n + (size_t)(32 * w + 16 * s + lr) * HID + ks * 32 + lk * 8);
  }
  const float b2a = b2[32 * w + lr];
  const float b2b = b2[32 * w + 16 + lr];
  const float4 bb0 = *(const float4*)&b1[8 * lpos];      // features 8p..8p+3
  const float4 bb1 = *(const float4*)&b1[8 * lpos + 4];  // features 8p+4..8p+7
  const float ms = (lgrp == 0) ? 1.f : 0.f;              // self-term gate

  const int m0 = blockIdx.x * 32;

  // ---- phase A prefetch: deg + padded lane-indices for all 8 rows ----
  int degs[8];
  int eidxs[8];
#pragma unroll
  for (int ri = 0; ri < 8; ++ri) {
    int node = m0 + 8 * w + ri;
    if (node >= n) node = n - 1;
    int d = cnt[node];
    d = d > CAP ? CAP : d;
    degs[ri] = d;
    const int e = bsrc[(size_t)node * CAP + l];
    eidxs[ri] = (l < d) ? e : n;  // pad lanes -> sentinel zero row
  }
  // ---- phase A: gather 8 rows per wave; 16-edge steps (4 loads in flight) + 8-edge tail ----
#pragma unroll
  for (int ri = 0; ri < 8; ++ri) {
    const int row = 8 * w + ri;
    int node = m0 + row;
    if (node >= n) node = n - 1;
    const int deg = degs[ri];
    const int deg8 = (deg + 7) & ~7;
    const int eidx = eidxs[ri];
    const uint4 sv = *(const uint4*)(U + (size_t)node * 64 + 4 * lpos);  // self row chunk
    float a0 = ms * bflo(sv.x), a1 = ms * bfhi(sv.x);
    float a2 = ms * bflo(sv.y), a3 = ms * bfhi(sv.y);
    float a4 = ms * bflo(sv.z), a5 = ms * bfhi(sv.z);
    float a6 = ms * bflo(sv.w), a7 = ms * bfhi(sv.w);
    int k = 0;
    for (; k + 15 < deg; k += 16) {  // 16 edges per iter, 4 loads in flight
      const int e0 = __shfl(eidx, k + lgrp);
      const int e1 = __shfl(eidx, k + 4 + lgrp);
      const int e2 = __shfl(eidx, k + 8 + lgrp);
      const int e3 = __shfl(eidx, k + 12 + lgrp);
      const uint4 u0 = *(const uint4*)(U + (size_t)e0 * 64 + 4 * lpos);
      const uint4 u1 = *(const uint4*)(U + (size_t)e1 * 64 + 4 * lpos);
      const uint4 u2 = *(const uint4*)(U + (size_t)e2 * 64 + 4 * lpos);
      const uint4 u3 = *(const uint4*)(U + (size_t)e3 * 64 + 4 * lpos);
      a0 += bflo(u0.x); a1 += bfhi(u0.x); a2 += bflo(u0.y); a3 += bfhi(u0.y);
      a4 += bflo(u0.z); a5 += bfhi(u0.z); a6 += bflo(u0.w); a7 += bfhi(u0.w);
      a0 += bflo(u1.x); a1 += bfhi(u1.x); a2 += bflo(u1.y); a3 += bfhi(u1.y);
      a4 += bflo(u1.z); a5 += bfhi(u1.z); a6 += bflo(u1.w); a7 += bfhi(u1.w);
      a0 += bflo(u2.x); a1 += bfhi(u2.x); a2 += bflo(u2.y); a3 += bfhi(u2.y);
      a4 += bflo(u2.z); a5 += bfhi(u2.z); a6 += bflo(u2.w); a7 += bfhi(u2.w);
      a0 += bflo(u3.x); a1 += bfhi(u3.x); a2 += bflo(u3.y); a3 += bfhi(u3.y);
      a4 += bflo(u3.z); a5 += bfhi(u3.z); a6 += bflo(u3.w); a7 += bfhi(u3.w);
    }
    for (; k < deg8; k += 8) {  // tail: 8 edges, 2 loads (pads hit sentinel zero row)
      const int e0 = __shfl(eidx, k + lgrp);
      const int e1 = __shfl(eidx, k + 4 + lgrp);
      const uint4 u0 = *(const uint4*)(U + (size_t)e0 * 64 + 4 * lpos);
      const uint4 u1 = *(const uint4*)(U + (size_t)e1 * 64 + 4 * lpos);
      a0 += bflo(u0.x); a1 += bfhi(u0.x); a2 += bflo(u0.y); a3 += bfhi(u0.y);
      a4 += bflo(u0.z); a5 += bfhi(u0.z); a6 += bflo(u0.w); a7 += bfhi(u0.w);
      a0 += bflo(u1.x); a1 += bfhi(u1.x); a2 += bflo(u1.y); a3 += bfhi(u1.y);
      a4 += bflo(u1.z); a5 += bfhi(u1.z); a6 += bflo(u1.w); a7 += bfhi(u1.w);
    }
    // fold the 4 lane-groups
    a0 += __shfl_xor(a0, 16); a0 += __shfl_xor(a0, 32);
    a1 += __shfl_xor(a1, 16); a1 += __shfl_xor(a1, 32);
    a2 += __shfl_xor(a2, 16); a2 += __shfl_xor(a2, 32);
    a3 += __shfl_xor(a3, 16); a3 += __shfl_xor(a3, 32);
    a4 += __shfl_xor(a4, 16); a4 += __shfl_xor(a4, 32);
    a5 += __shfl_xor(a5, 16); a5 += __shfl_xor(a5, 32);
    a6 += __shfl_xor(a6, 16); a6 += __shfl_xor(a6, 32);
    a7 += __shfl_xor(a7, 16); a7 += __shfl_xor(a7, 32);
    if (lgrp == 0) {
      const int swz = (row & 7) << 2;
      uint4 o;
      o.x = (unsigned int)f2bf(fmaxf(a0 + bb0.x, 0.f)) |
            ((unsigned int)f2bf(fmaxf(a1 + bb0.y, 0.f)) << 16);
      o.y = (unsigned int)f2bf(fmaxf(a2 + bb0.z, 0.f)) |
            ((unsigned int)f2bf(fmaxf(a3 + bb0.w, 0.f)) << 16);
      o.z = (unsigned int)f2bf(fmaxf(a4 + bb1.x, 0.f)) |
            ((unsigned int)f2bf(fmaxf(a5 + bb1.y, 0.f)) << 16);
      o.w = (unsigned int)f2bf(fmaxf(a6 + bb1.z, 0.f)) |
            ((unsigned int)f2bf(fmaxf(a7 + bb1.w, 0.f)) << 16);
      *(uint4*)&sA[row * 64 + ((4 * lpos) ^ swz)] = o;
    }
  }
  __syncthreads();

  // ---- phase B: GEMM W2 (reads sA) ----
  f32x4 acc00 = {0.f, 0.f, 0.f, 0.f}, acc01 = acc00, acc10 = acc00, acc11 = acc00;
#pragma unroll
  for (int mt = 0; mt < 2; ++mt) {
    const int row = 16 * mt + lr;
    const int swz = (row & 7) << 2;
#pragma unroll
    for (int ks = 0; ks < 4; ++ks) {
      const bfrag a = *(const bfrag*)&sA[row * 64 + ((ks * 16 + lk * 4) ^ swz)];
      if (mt == 0) {
        acc00 = __builtin_amdgcn_mfma_f32_16x16x32_bf16(a, w2f[0][ks], acc00, 0, 0, 0);
        acc01 = __builtin_amdgcn_mfma_f32_16x16x32_bf16(a, w2f[1][ks], acc01, 0, 0, 0);
      } else {
        acc10 = __builtin_amdgcn_mfma_f32_16x16x32_bf16(a, w2f[0][ks], acc10, 0, 0, 0);
        acc11 = __builtin_amdgcn_mfma_f32_16x16x32_bf16(a, w2f[1][ks], acc11, 0, 0, 0);
      }
    }
  }
  if (LAST) {
#pragma unroll
    for (int mt = 0; mt < 2; ++mt) {
#pragma unroll
      for (int s = 0; s < 2; ++s) {
        const f32x4 a = mt == 0 ? (s == 0 ? acc00 : acc01) : (s == 0 ? acc10 : acc11);
        const float bb = s == 0 ? b2a : b2b;
        const int col = 32 * w + 16 * s + lr;
#pragma unroll
        for (int r = 0; r < 4; ++r) {
          const int row = m0 + 16 * mt + 4 * lk + r;
          if (row < n) Y[(size_t)row * HID + col] = f2bf(a[r] + bb);
        }
      }
    }
  } else {
    unsigned short* sB16 = (unsigned short*)sB;
#pragma unroll
    for (int mt = 0; mt < 2; ++mt) {
#pragma unroll
      for (int s = 0; s < 2; ++s) {
        const f32x4 a = mt == 0 ? (s == 0 ? acc00 : acc01) : (s == 0 ? acc10 : acc11);
        const float bb = s == 0 ? b2a : b2b;
        const int col = 32 * w + 16 * s + lr;
#pragma unroll
        for (int r = 0; r < 4; ++r) {
          const int rowL = 16 * mt + 4 * lk + r;
          const int cu = (col >> 1) ^ ((rowL & 7) << 2);
          sB16[rowL * 128 + cu * 2 + (col & 1)] = f2bf(fmaxf(a[r] + bb, 0.f));
        }
      }
    }
    __syncthreads();
    // ---- phase C: GEMM W1next (reads sB), write u_{i+1} ----
    f32x4 u00 = {0.f, 0.f, 0.f, 0.f}, u01 = u00, u10 = u00, u11 = u00;
#pragma unroll
    for (int mt = 0; mt < 2; ++mt) {
      const int row = 16 * mt + lr;
      const int swz = (row & 7) << 2;
#pragma unroll
      for (int ks = 0; ks < 4; ++ks) {
        const bfrag a = *(const bfrag*)&sB[row * 64 + ((ks * 16 + lk * 4) ^ swz)];
        if (mt == 0) {
          u00 = __builtin_amdgcn_mfma_f32_16x16x32_bf16(a, w1f[0][ks], u00, 0, 0, 0);
          u01 = __builtin_amdgcn_mfma_f32_16x16x32_bf16(a, w1f[1][ks], u01, 0, 0, 0);
        } else {
          u10 = __builtin_amdgcn_mfma_f32_16x16x32_bf16(a, w1f[0][ks], u10, 0, 0, 0);
          u11 = __builtin_amdgcn_mfma_f32_16x16x32_bf16(a, w1f[1][ks], u11, 0, 0, 0);
        }
      }
    }
#pragma unroll
    for (int mt = 0; mt < 2; ++mt) {
#pragma unroll
      for (int s = 0; s < 2; ++s) {
        const f32x4 a = mt == 0 ? (s == 0 ? u00 : u01) : (s == 0 ? u10 : u11);
        const int col = 32 * w + 16 * s + lr;
#pragma unroll
        for (int r = 0; r < 4; ++r) {
          const int row = m0 + 16 * mt + 4 * lk + r;
          if (row < n) Y[(size_t)row * HID + col] = f2bf(a[r]);
        }
      }
    }
  }
}

// ---------------- pooling + predict MLP (2-way node-parallel accumulate) ----------------

__global__ __launch_bounds__(256) void k_pool(const unsigned short* __restrict__ X,
                                              const int* __restrict__ goff,
                                              const float* __restrict__ Wp1,
                                              const float* __restrict__ bp1,
                                              const float* __restrict__ Wp2,
                                              const float* __restrict__ bp2,
                                              float* __restrict__ out, int G) {
  __shared__ float sgp[2][HID];
  __shared__ float sg[HID];
  __shared__ float sred[HID];
  const int g = blockIdx.x;
  const int t = threadIdx.x;
  const int f = t & 127, h = t >> 7;
  const int n0 = goff[g], n1 = goff[g + 1];
  float c0 = 0.f, c1 = 0.f, c2 = 0.f, c3 = 0.f;
  int nn = n0 + h;
  for (; nn + 6 < n1; nn += 8) {  // halves interleave by 2; 4 nodes per half per iter
    c0 += __uint_as_float((unsigned int)X[(size_t)nn * HID + f] << 16);
    c1 += __uint_as_float((unsigned int)X[(size_t)(nn + 2) * HID + f] << 16);
    c2 += __uint_as_float((unsigned int)X[(size_t)(nn + 4) * HID + f] << 16);
    c3 += __uint_as_float((unsigned int)X[(size_t)(nn + 6) * HID + f] << 16);
  }
  for (; nn < n1; nn += 2) c0 += __uint_as_float((unsigned int)X[(size_t)nn * HID + f] << 16);
  sgp[h][f] = (c0 + c1) + (c2 + c3);
  __syncthreads();
  if (t < HID) sg[t] = sgp[0][t] + sgp[1][t];
  __syncthreads();
  if (t < HID) {
    float a0 = 0.f, a1 = 0.f, a2 = 0.f, a3 = 0.f;
#pragma unroll
    for (int k4 = 0; k4 < 32; ++k4) {
      float4 wv = *(const float4*)&Wp1[f * HID + k4 * 4];
      float4 xv = *(const float4*)&sg[k4 * 4];
      a0 += wv.x * xv.x; a1 += wv.y * xv.y; a2 += wv.z * xv.z; a3 += wv.w * xv.w;
    }
    float hh = fmaxf(bp1[f] + ((a0 + a1) + (a2 + a3)), 0.f);
    sred[f] = Wp2[f] * hh;
  }
  __syncthreads();
  for (int s = 64; s > 0; s >>= 1) {
    if (t < s) sred[t] += sred[t + s];
    __syncthreads();
  }
  if (t == 0) out[g] = sred[0] + bp2[0];
}

// ---------------- launch ----------------

extern "C" void kernel_launch(void* const* d_in, const int* in_sizes, int n_in,
                              void* d_out, int out_size, void* d_ws, size_t ws_size,
                              hipStream_t stream) {
  const int*   z      = (const int*)d_in[0];
  const float* pos    = (const float*)d_in[1];
  const int*   ei     = (const int*)d_in[2];
  const int*   batch  = (const int*)d_in[3];
  const float* emb    = (const float*)d_in[4];
  const float* W_pos  = (const float*)d_in[5];
  const float* b_pos  = (const float*)d_in[6];
  const float* W_comb = (const float*)d_in[7];
  const float* b_comb = (const float*)d_in[8];
  const float* gW1    = (const float*)d_in[9];
  const float* gb1    = (const float*)d_in[10];
  const float* gW2    = (const float*)d_in[11];
  const float* gb2    = (const float*)d_in[12];
  const float* Wp1    = (const float*)d_in[13];
  const float* bp1    = (const float*)d_in[14];
  const float* Wp2    = (const float*)d_in[15];
  const float* bp2    = (const float*)d_in[16];
  float* out = (float*)d_out;

  const int N = in_sizes[0];
  const int E = in_sizes[2] / 2;
  const int G = out_size;
  const int* srcp = ei;
  const int* dstp = ei + E;
  const int ntiles = (N + 31) / 32;
  const int nGoff = (G + 1 + 255) / 256;

  char* w = (char*)d_ws;
  unsigned short* Ub  = (unsigned short*)w; w += align256((size_t)(N + 1) * 128 * 2);
  unsigned short* Vb  = (unsigned short*)w; w += align256((size_t)(N + 1) * 128 * 2);
  unsigned short* Wcb = (unsigned short*)w; w += align256((size_t)128 * 256 * 2);
  unsigned short* W1b = (unsigned short*)w; w += align256((size_t)3 * 128 * 128 * 2);
  unsigned short* W2b = (unsigned short*)w; w += align256((size_t)3 * 128 * 128 * 2);
  int* cnt  = (int*)w; w += align256((size_t)N * 4);
  int* bsrc = (int*)w; w += align256((size_t)N * CAP * 4);
  int* goff = (int*)w; w += align256((size_t)(G + 1) * 4);

  hipMemsetAsync(cnt, 0, (size_t)N * 4, stream);

  k_prep<<<NBK + NWC + nGoff, 256, 0, stream>>>(
      srcp, dstp, cnt, bsrc, E, N, W_comb, gW1, gW2, Wcb, W1b, W2b, batch, goff, G,
      (unsigned int*)(Ub + (size_t)N * 128), (unsigned int*)(Vb + (size_t)N * 128));

  // u1 = W1[0] @ relu(Wc @ [emb||pe] + bc)
  k_init_mm<<<ntiles, 256, 0, stream>>>(z, pos, emb, W_pos, b_pos, Wcb, b_comb,
                                        W1b, Ub, N);

  // layer 0: u2
  k_layer<0><<<ntiles, 256, 0, stream>>>((const unsigned int*)Ub, cnt, bsrc, gb1,
                                         W2b, gb2, W1b + (size_t)1 * 128 * 128, Vb, N);
  // layer 1: u3
  k_layer<0><<<ntiles, 256, 0, stream>>>((const unsigned int*)Vb, cnt, bsrc, gb1 + 128,
                                         W2b + (size_t)1 * 128 * 128, gb2 + 128,
                                         W1b + (size_t)2 * 128 * 128, Ub, N);
  // layer 2: x3 (no relu, no W1next)
  k_layer<1><<<ntiles, 256, 0, stream>>>((const unsigned int*)Ub, cnt, bsrc, gb1 + 256,
                                         W2b + (size_t)2 * 128 * 128, gb2 + 256,
                                         (const unsigned short*)nullptr, Vb, N);

  k_pool<<<G, 256, 0, stream>>>(Vb, goff, Wp1, bp1, Wp2, bp2, out, G);
}

// Round 15
// 402.748 us; speedup vs baseline: 1.0273x; 1.0273x over previous
//
#include <hip/hip_runtime.h>
#include <hip/hip_bf16.h>

#define HID 128
#define CAP 64   // bucket capacity: deg ~ Poisson(16), P(any node >= 64) ~ 1e-14
#define NBK 2048 // scatter blocks in k_prep
#define NWC 192  // weight-convert blocks (covers 3*128*128 = 49152 >= 128*256)

typedef __attribute__((ext_vector_type(8))) short bfrag;   // 8 bf16 = 4 VGPR
typedef __attribute__((ext_vector_type(4))) float f32x4;

static inline size_t align256(size_t x) { return (x + 255) & ~(size_t)255; }

__device__ __forceinline__ unsigned short f2bf(float f) {
  unsigned int x = __float_as_uint(f);
  unsigned int r = x + 0x7fffu + ((x >> 16) & 1u);  // RNE
  return (unsigned short)(r >> 16);
}
__device__ __forceinline__ float bflo(unsigned int u) { return __uint_as_float(u << 16); }
__device__ __forceinline__ float bfhi(unsigned int u) { return __uint_as_float(u & 0xffff0000u); }

// ---------------- prep: XCD-sliced scatter + weight converts + goff + sentinel zero ------
// Register-lean (no LDS, ~4 VGPR in scatter role) so scatter waves keep full occupancy
// for atomic-latency hiding (round-10 lesson: merging with MFMA init throttled it).

__global__ __launch_bounds__(256) void k_prep(const int* __restrict__ src,
                                              const int* __restrict__ dst,
                                              int* __restrict__ cnt,
                                              int* __restrict__ bsrc, int E, int N,
                                              const float* __restrict__ W_comb,
                                              const float* __restrict__ gW1,
                                              const float* __restrict__ gW2,
                                              unsigned short* __restrict__ Wcb,
                                              unsigned short* __restrict__ W1b,
                                              unsigned short* __restrict__ W2b,
                                              const int* __restrict__ batch,
                                              int* __restrict__ goff, int G,
                                              unsigned int* __restrict__ UbZ,
                                              unsigned int* __restrict__ VbZ) {
  const int bid = blockIdx.x;
  const int tid = threadIdx.x;
  if (bid < NBK) {  // ---- XCD-sliced bucket scatter ----
    const int slice = bid & 7;
    const int sidx = bid >> 3;
    const int s_lo = (int)(((long long)slice * N) >> 3);
    const int s_hi = (int)(((long long)(slice + 1) * N) >> 3);
    for (int e = sidx * 256 + tid; e < E; e += (NBK / 8) * 256) {
      int d = dst[e];
      if (d >= s_lo && d < s_hi) {
        int slot = atomicAdd(&cnt[d], 1);
        if (slot < CAP) bsrc[(size_t)d * CAP + slot] = src[e];
      }
    }
  } else if (bid < NBK + NWC) {  // ---- Wc/gW1/gW2 f32->bf16 ----
    int i = (bid - NBK) * 256 + tid;
    if (i < 128 * 256) Wcb[i] = f2bf(W_comb[i]);
    if (i < 3 * 128 * 128) {
      W1b[i] = f2bf(gW1[i]);
      W2b[i] = f2bf(gW2[i]);
    }
  } else {  // ---- goff binary search + sentinel zero rows ----
    int g = (bid - NBK - NWC) * 256 + tid;
    if (g <= G) {
      int lo = 0, hi = N;
      while (lo < hi) {
        int mid = (lo + hi) >> 1;
        if (batch[mid] < g) lo = mid + 1; else hi = mid;
      }
      goff[g] = lo;
    }
    if (bid == NBK + NWC) {
      if (tid >= 64 && tid < 128) UbZ[tid - 64] = 0;
      else if (tid >= 128 && tid < 192) VbZ[tid - 128] = 0;
    }
  }
}

// ---------------- fused init: [emb(z)||pos-proj] -> GEMM Wc(K=256) -> relu -> GEMM W1[0] ----
// Weights pre-converted to bf16 by k_prep (round-11 lesson: in-register f32 convert
// cost 108 VGPR / 19% occupancy / 93us — as much as a whole layer).

__global__ __launch_bounds__(256, 2) void k_init_mm(const int* __restrict__ z,
                                                    const float* __restrict__ pos,
                                                    const float* __restrict__ emb,
                                                    const float* __restrict__ W_pos,
                                                    const float* __restrict__ b_pos,
                                                    const unsigned short* __restrict__ Wcb,
                                                    const float* __restrict__ b_comb,
                                                    const unsigned short* __restrict__ W1n,
                                                    unsigned short* __restrict__ Y, int n) {
  __shared__ unsigned int sE[32 * 128];  // input rows (256 bf16), swizzled
  __shared__ unsigned int sB[32 * 64];   // intermediate x rows (128 bf16), swizzled
  const int t = threadIdx.x;
  const int w = t >> 6, l = t & 63, lr = l & 15, lk = l >> 4;

  bfrag wcf[2][8];
#pragma unroll
  for (int s = 0; s < 2; ++s)
#pragma unroll
    for (int ks = 0; ks < 8; ++ks)
      wcf[s][ks] = *(const bfrag*)(Wcb + (size_t)(32 * w + 16 * s + lr) * 256 + ks * 32 + lk * 8);
  bfrag w1f[2][4];
#pragma unroll
  for (int s = 0; s < 2; ++s)
#pragma unroll
    for (int ks = 0; ks < 4; ++ks)
      w1f[s][ks] = *(const bfrag*)(W1n + (size_t)(32 * w + 16 * s + lr) * HID + ks * 32 + lk * 8);
  const float bias0 = b_comb[32 * w + lr];
  const float bias1 = b_comb[32 * w + 16 + lr];

  const int m0 = blockIdx.x * 32;
  {
    const int r = t >> 3, i = t & 7;
    int node = m0 + r;
    if (node >= n) node = n - 1;
    const int zz = z[node];
    const float p0 = pos[node * 3 + 0], p1 = pos[node * 3 + 1], p2 = pos[node * 3 + 2];
    const int swz = (r & 7) << 2;
#pragma unroll
    for (int k = 0; k < 16; ++k) {
      const int j = i + k * 8;
      float v0, v1;
      if (j < 64) {
        const float2 ev = *(const float2*)&emb[(size_t)zz * 128 + 2 * j];
        v0 = ev.x; v1 = ev.y;
      } else {
        const int f0 = 2 * j - 128;
        v0 = b_pos[f0] + W_pos[f0 * 3] * p0 + W_pos[f0 * 3 + 1] * p1 + W_pos[f0 * 3 + 2] * p2;
        v1 = b_pos[f0 + 1] + W_pos[f0 * 3 + 3] * p0 + W_pos[f0 * 3 + 4] * p1 +
             W_pos[f0 * 3 + 5] * p2;
      }
      sE[r * 128 + (j ^ swz)] = (unsigned int)f2bf(v0) | ((unsigned int)f2bf(v1) << 16);
    }
  }
  __syncthreads();

  f32x4 acc00 = {0.f, 0.f, 0.f, 0.f}, acc01 = acc00, acc10 = acc00, acc11 = acc00;
#pragma unroll
  for (int mt = 0; mt < 2; ++mt) {
    const int row = 16 * mt + lr;
    const int swz = (row & 7) << 2;
#pragma unroll
    for (int ks = 0; ks < 8; ++ks) {
      const bfrag a = *(const bfrag*)&sE[row * 128 + ((ks * 16 + lk * 4) ^ swz)];
      if (mt == 0) {
        acc00 = __builtin_amdgcn_mfma_f32_16x16x32_bf16(a, wcf[0][ks], acc00, 0, 0, 0);
        acc01 = __builtin_amdgcn_mfma_f32_16x16x32_bf16(a, wcf[1][ks], acc01, 0, 0, 0);
      } else {
        acc10 = __builtin_amdgcn_mfma_f32_16x16x32_bf16(a, wcf[0][ks], acc10, 0, 0, 0);
        acc11 = __builtin_amdgcn_mfma_f32_16x16x32_bf16(a, wcf[1][ks], acc11, 0, 0, 0);
      }
    }
  }
  {
    unsigned short* sB16 = (unsigned short*)sB;
#pragma unroll
    for (int mt = 0; mt < 2; ++mt) {
#pragma unroll
      for (int s = 0; s < 2; ++s) {
        const f32x4 a = mt == 0 ? (s == 0 ? acc00 : acc01) : (s == 0 ? acc10 : acc11);
        const float bb = s == 0 ? bias0 : bias1;
        const int col = 32 * w + 16 * s + lr;
#pragma unroll
        for (int r = 0; r < 4; ++r) {
          const int rowL = 16 * mt + 4 * lk + r;
          const int cu = (col >> 1) ^ ((rowL & 7) << 2);
          sB16[rowL * 128 + cu * 2 + (col & 1)] = f2bf(fmaxf(a[r] + bb, 0.f));
        }
      }
    }
  }
  __syncthreads();

  f32x4 u00 = {0.f, 0.f, 0.f, 0.f}, u01 = u00, u10 = u00, u11 = u00;
#pragma unroll
  for (int mt = 0; mt < 2; ++mt) {
    const int row = 16 * mt + lr;
    const int swz = (row & 7) << 2;
#pragma unroll
    for (int ks = 0; ks < 4; ++ks) {
      const bfrag a = *(const bfrag*)&sB[row * 64 + ((ks * 16 + lk * 4) ^ swz)];
      if (mt == 0) {
        u00 = __builtin_amdgcn_mfma_f32_16x16x32_bf16(a, w1f[0][ks], u00, 0, 0, 0);
        u01 = __builtin_amdgcn_mfma_f32_16x16x32_bf16(a, w1f[1][ks], u01, 0, 0, 0);
      } else {
        u10 = __builtin_amdgcn_mfma_f32_16x16x32_bf16(a, w1f[0][ks], u10, 0, 0, 0);
        u11 = __builtin_amdgcn_mfma_f32_16x16x32_bf16(a, w1f[1][ks], u11, 0, 0, 0);
      }
    }
  }
#pragma unroll
  for (int mt = 0; mt < 2; ++mt) {
#pragma unroll
    for (int s = 0; s < 2; ++s) {
      const f32x4 a = mt == 0 ? (s == 0 ? u00 : u01) : (s == 0 ? u10 : u11);
      const int col = 32 * w + 16 * s + lr;
#pragma unroll
      for (int r = 0; r < 4; ++r) {
        const int row = m0 + 16 * mt + 4 * lk + r;
        if (row < n) Y[(size_t)row * HID + col] = f2bf(a[r]);
      }
    }
  }
}

// ---------------- fused layer: gather(u)+b1+relu -> GEMM W2(+b2,relu) -> GEMM W1next --------
// Round-13 proven configuration: 8-edge branch-free steps (2 uint4 loads in flight),
// sentinel-zero-row padding, launch_bounds(256,4) -> 64 VGPR zero-spill, 36% occupancy,
// 92.7us/layer at 196MB L2-miss traffic (~2.1 TB/s, within ~13% of random-line floor).
// Round-14 lesson: 4-deep window spills (WRITE 25->87MB, 102us) — 2-deep is the optimum.

template <int LAST>
__global__ __launch_bounds__(256, 4) void k_layer(const unsigned int* __restrict__ U,
                                                  const int* __restrict__ cnt,
                                                  const int* __restrict__ bsrc,
                                                  const float* __restrict__ b1,
                                                  const unsigned short* __restrict__ W2b,
                                                  const float* __restrict__ b2,
                                                  const unsigned short* __restrict__ W1n,
                                                  unsigned short* __restrict__ Y, int n) {
  __shared__ unsigned int sA[32 * 64];  // h rows (gathered, post-relu), swizzled
  __shared__ unsigned int sB[32 * 64];  // x rows (W2 output), swizzled
  const int t = threadIdx.x;
  const int w = t >> 6, l = t & 63, lr = l & 15, lk = l >> 4;
  const int lgrp = lk, lpos = lr;  // gather aliases: group 0..3, position 0..15

  bfrag w2f[2][4];
#pragma unroll
  for (int s = 0; s < 2; ++s)
#pragma unroll
    for (int ks = 0; ks < 4; ++ks)
      w2f[s][ks] = *(const bfrag*)(W2b + (size_t)(32 * w + 16 * s + lr) * HID + ks * 32 + lk * 8);
  bfrag w1f[2][4];
  if (!LAST) {
#pragma unroll
    for (int s = 0; s < 2; ++s)
#pragma unroll
      for (int ks = 0; ks < 4; ++ks)
        w1f[s][ks] = *(const bfrag*)(W1n + (size_t)(32 * w + 16 * s + lr) * HID + ks * 32 + lk * 8);
  }
  const float b2a = b2[32 * w + lr];
  const float b2b = b2[32 * w + 16 + lr];
  const float4 bb0 = *(const float4*)&b1[8 * lpos];      // features 8p..8p+3
  const float4 bb1 = *(const float4*)&b1[8 * lpos + 4];  // features 8p+4..8p+7
  const float ms = (lgrp == 0) ? 1.f : 0.f;              // self-term gate

  const int m0 = blockIdx.x * 32;

  // ---- phase A prefetch: deg + padded lane-indices for all 8 rows ----
  int degs[8];
  int eidxs[8];
#pragma unroll
  for (int ri = 0; ri < 8; ++ri) {
    int node = m0 + 8 * w + ri;
    if (node >= n) node = n - 1;
    int d = cnt[node];
    d = d > CAP ? CAP : d;
    degs[ri] = d;
    const int e = bsrc[(size_t)node * CAP + l];
    eidxs[ri] = (l < d) ? e : n;  // pad lanes -> sentinel zero row
  }
  // ---- phase A: gather 8 rows per wave, branch-free 8-edge steps ----
#pragma unroll
  for (int ri = 0; ri < 8; ++ri) {
    const int row = 8 * w + ri;
    int node = m0 + row;
    if (node >= n) node = n - 1;
    const int deg8 = (degs[ri] + 7) & ~7;
    const int eidx = eidxs[ri];
    const uint4 sv = *(const uint4*)(U + (size_t)node * 64 + 4 * lpos);  // self row chunk
    float a0 = ms * bflo(sv.x), a1 = ms * bfhi(sv.x);
    float a2 = ms * bflo(sv.y), a3 = ms * bfhi(sv.y);
    float a4 = ms * bflo(sv.z), a5 = ms * bfhi(sv.z);
    float a6 = ms * bflo(sv.w), a7 = ms * bfhi(sv.w);
    for (int k = 0; k < deg8; k += 8) {  // 8 edges per iter, 2 loads in flight
      const int e0 = __shfl(eidx, k + lgrp);
      const int e1 = __shfl(eidx, k + 4 + lgrp);
      const uint4 u0 = *(const uint4*)(U + (size_t)e0 * 64 + 4 * lpos);
      const uint4 u1 = *(const uint4*)(U + (size_t)e1 * 64 + 4 * lpos);
      a0 += bflo(u0.x); a1 += bfhi(u0.x); a2 += bflo(u0.y); a3 += bfhi(u0.y);
      a4 += bflo(u0.z); a5 += bfhi(u0.z); a6 += bflo(u0.w); a7 += bfhi(u0.w);
      a0 += bflo(u1.x); a1 += bfhi(u1.x); a2 += bflo(u1.y); a3 += bfhi(u1.y);
      a4 += bflo(u1.z); a5 += bfhi(u1.z); a6 += bflo(u1.w); a7 += bfhi(u1.w);
    }
    // fold the 4 lane-groups
    a0 += __shfl_xor(a0, 16); a0 += __shfl_xor(a0, 32);
    a1 += __shfl_xor(a1, 16); a1 += __shfl_xor(a1, 32);
    a2 += __shfl_xor(a2, 16); a2 += __shfl_xor(a2, 32);
    a3 += __shfl_xor(a3, 16); a3 += __shfl_xor(a3, 32);
    a4 += __shfl_xor(a4, 16); a4 += __shfl_xor(a4, 32);
    a5 += __shfl_xor(a5, 16); a5 += __shfl_xor(a5, 32);
    a6 += __shfl_xor(a6, 16); a6 += __shfl_xor(a6, 32);
    a7 += __shfl_xor(a7, 16); a7 += __shfl_xor(a7, 32);
    if (lgrp == 0) {
      const int swz = (row & 7) << 2;
      uint4 o;
      o.x = (unsigned int)f2bf(fmaxf(a0 + bb0.x, 0.f)) |
            ((unsigned int)f2bf(fmaxf(a1 + bb0.y, 0.f)) << 16);
      o.y = (unsigned int)f2bf(fmaxf(a2 + bb0.z, 0.f)) |
            ((unsigned int)f2bf(fmaxf(a3 + bb0.w, 0.f)) << 16);
      o.z = (unsigned int)f2bf(fmaxf(a4 + bb1.x, 0.f)) |
            ((unsigned int)f2bf(fmaxf(a5 + bb1.y, 0.f)) << 16);
      o.w = (unsigned int)f2bf(fmaxf(a6 + bb1.z, 0.f)) |
            ((unsigned int)f2bf(fmaxf(a7 + bb1.w, 0.f)) << 16);
      *(uint4*)&sA[row * 64 + ((4 * lpos) ^ swz)] = o;
    }
  }
  __syncthreads();

  // ---- phase B: GEMM W2 (reads sA) ----
  f32x4 acc00 = {0.f, 0.f, 0.f, 0.f}, acc01 = acc00, acc10 = acc00, acc11 = acc00;
#pragma unroll
  for (int mt = 0; mt < 2; ++mt) {
    const int row = 16 * mt + lr;
    const int swz = (row & 7) << 2;
#pragma unroll
    for (int ks = 0; ks < 4; ++ks) {
      const bfrag a = *(const bfrag*)&sA[row * 64 + ((ks * 16 + lk * 4) ^ swz)];
      if (mt == 0) {
        acc00 = __builtin_amdgcn_mfma_f32_16x16x32_bf16(a, w2f[0][ks], acc00, 0, 0, 0);
        acc01 = __builtin_amdgcn_mfma_f32_16x16x32_bf16(a, w2f[1][ks], acc01, 0, 0, 0);
      } else {
        acc10 = __builtin_amdgcn_mfma_f32_16x16x32_bf16(a, w2f[0][ks], acc10, 0, 0, 0);
        acc11 = __builtin_amdgcn_mfma_f32_16x16x32_bf16(a, w2f[1][ks], acc11, 0, 0, 0);
      }
    }
  }
  if (LAST) {
#pragma unroll
    for (int mt = 0; mt < 2; ++mt) {
#pragma unroll
      for (int s = 0; s < 2; ++s) {
        const f32x4 a = mt == 0 ? (s == 0 ? acc00 : acc01) : (s == 0 ? acc10 : acc11);
        const float bb = s == 0 ? b2a : b2b;
        const int col = 32 * w + 16 * s + lr;
#pragma unroll
        for (int r = 0; r < 4; ++r) {
          const int row = m0 + 16 * mt + 4 * lk + r;
          if (row < n) Y[(size_t)row * HID + col] = f2bf(a[r] + bb);
        }
      }
    }
  } else {
    unsigned short* sB16 = (unsigned short*)sB;
#pragma unroll
    for (int mt = 0; mt < 2; ++mt) {
#pragma unroll
      for (int s = 0; s < 2; ++s) {
        const f32x4 a = mt == 0 ? (s == 0 ? acc00 : acc01) : (s == 0 ? acc10 : acc11);
        const float bb = s == 0 ? b2a : b2b;
        const int col = 32 * w + 16 * s + lr;
#pragma unroll
        for (int r = 0; r < 4; ++r) {
          const int rowL = 16 * mt + 4 * lk + r;
          const int cu = (col >> 1) ^ ((rowL & 7) << 2);
          sB16[rowL * 128 + cu * 2 + (col & 1)] = f2bf(fmaxf(a[r] + bb, 0.f));
        }
      }
    }
    __syncthreads();
    // ---- phase C: GEMM W1next (reads sB), write u_{i+1} ----
    f32x4 u00 = {0.f, 0.f, 0.f, 0.f}, u01 = u00, u10 = u00, u11 = u00;
#pragma unroll
    for (int mt = 0; mt < 2; ++mt) {
      const int row = 16 * mt + lr;
      const int swz = (row & 7) << 2;
#pragma unroll
      for (int ks = 0; ks < 4; ++ks) {
        const bfrag a = *(const bfrag*)&sB[row * 64 + ((ks * 16 + lk * 4) ^ swz)];
        if (mt == 0) {
          u00 = __builtin_amdgcn_mfma_f32_16x16x32_bf16(a, w1f[0][ks], u00, 0, 0, 0);
          u01 = __builtin_amdgcn_mfma_f32_16x16x32_bf16(a, w1f[1][ks], u01, 0, 0, 0);
        } else {
          u10 = __builtin_amdgcn_mfma_f32_16x16x32_bf16(a, w1f[0][ks], u10, 0, 0, 0);
          u11 = __builtin_amdgcn_mfma_f32_16x16x32_bf16(a, w1f[1][ks], u11, 0, 0, 0);
        }
      }
    }
#pragma unroll
    for (int mt = 0; mt < 2; ++mt) {
#pragma unroll
      for (int s = 0; s < 2; ++s) {
        const f32x4 a = mt == 0 ? (s == 0 ? u00 : u01) : (s == 0 ? u10 : u11);
        const int col = 32 * w + 16 * s + lr;
#pragma unroll
        for (int r = 0; r < 4; ++r) {
          const int row = m0 + 16 * mt + 4 * lk + r;
          if (row < n) Y[(size_t)row * HID + col] = f2bf(a[r]);
        }
      }
    }
  }
}

// ---------------- pooling + predict MLP (2-way node-parallel accumulate) ----------------

__global__ __launch_bounds__(256) void k_pool(const unsigned short* __restrict__ X,
                                              const int* __restrict__ goff,
                                              const float* __restrict__ Wp1,
                                              const float* __restrict__ bp1,
                                              const float* __restrict__ Wp2,
                                              const float* __restrict__ bp2,
                                              float* __restrict__ out, int G) {
  __shared__ float sgp[2][HID];
  __shared__ float sg[HID];
  __shared__ float sred[HID];
  const int g = blockIdx.x;
  const int t = threadIdx.x;
  const int f = t & 127, h = t >> 7;
  const int n0 = goff[g], n1 = goff[g + 1];
  float c0 = 0.f, c1 = 0.f, c2 = 0.f, c3 = 0.f;
  int nn = n0 + h;
  for (; nn + 6 < n1; nn += 8) {  // halves interleave by 2; 4 nodes per half per iter
    c0 += __uint_as_float((unsigned int)X[(size_t)nn * HID + f] << 16);
    c1 += __uint_as_float((unsigned int)X[(size_t)(nn + 2) * HID + f] << 16);
    c2 += __uint_as_float((unsigned int)X[(size_t)(nn + 4) * HID + f] << 16);
    c3 += __uint_as_float((unsigned int)X[(size_t)(nn + 6) * HID + f] << 16);
  }
  for (; nn < n1; nn += 2) c0 += __uint_as_float((unsigned int)X[(size_t)nn * HID + f] << 16);
  sgp[h][f] = (c0 + c1) + (c2 + c3);
  __syncthreads();
  if (t < HID) sg[t] = sgp[0][t] + sgp[1][t];
  __syncthreads();
  if (t < HID) {
    float a0 = 0.f, a1 = 0.f, a2 = 0.f, a3 = 0.f;
#pragma unroll
    for (int k4 = 0; k4 < 32; ++k4) {
      float4 wv = *(const float4*)&Wp1[f * HID + k4 * 4];
      float4 xv = *(const float4*)&sg[k4 * 4];
      a0 += wv.x * xv.x; a1 += wv.y * xv.y; a2 += wv.z * xv.z; a3 += wv.w * xv.w;
    }
    float hh = fmaxf(bp1[f] + ((a0 + a1) + (a2 + a3)), 0.f);
    sred[f] = Wp2[f] * hh;
  }
  __syncthreads();
  for (int s = 64; s > 0; s >>= 1) {
    if (t < s) sred[t] += sred[t + s];
    __syncthreads();
  }
  if (t == 0) out[g] = sred[0] + bp2[0];
}

// ---------------- launch ----------------

extern "C" void kernel_launch(void* const* d_in, const int* in_sizes, int n_in,
                              void* d_out, int out_size, void* d_ws, size_t ws_size,
                              hipStream_t stream) {
  const int*   z      = (const int*)d_in[0];
  const float* pos    = (const float*)d_in[1];
  const int*   ei     = (const int*)d_in[2];
  const int*   batch  = (const int*)d_in[3];
  const float* emb    = (const float*)d_in[4];
  const float* W_pos  = (const float*)d_in[5];
  const float* b_pos  = (const float*)d_in[6];
  const float* W_comb = (const float*)d_in[7];
  const float* b_comb = (const float*)d_in[8];
  const float* gW1    = (const float*)d_in[9];
  const float* gb1    = (const float*)d_in[10];
  const float* gW2    = (const float*)d_in[11];
  const float* gb2    = (const float*)d_in[12];
  const float* Wp1    = (const float*)d_in[13];
  const float* bp1    = (const float*)d_in[14];
  const float* Wp2    = (const float*)d_in[15];
  const float* bp2    = (const float*)d_in[16];
  float* out = (float*)d_out;

  const int N = in_sizes[0];
  const int E = in_sizes[2] / 2;
  const int G = out_size;
  const int* srcp = ei;
  const int* dstp = ei + E;
  const int ntiles = (N + 31) / 32;
  const int nGoff = (G + 1 + 255) / 256;

  char* w = (char*)d_ws;
  unsigned short* Ub  = (unsigned short*)w; w += align256((size_t)(N + 1) * 128 * 2);
  unsigned short* Vb  = (unsigned short*)w; w += align256((size_t)(N + 1) * 128 * 2);
  unsigned short* Wcb = (unsigned short*)w; w += align256((size_t)128 * 256 * 2);
  unsigned short* W1b = (unsigned short*)w; w += align256((size_t)3 * 128 * 128 * 2);
  unsigned short* W2b = (unsigned short*)w; w += align256((size_t)3 * 128 * 128 * 2);
  int* cnt  = (int*)w; w += align256((size_t)N * 4);
  int* bsrc = (int*)w; w += align256((size_t)N * CAP * 4);
  int* goff = (int*)w; w += align256((size_t)(G + 1) * 4);

  hipMemsetAsync(cnt, 0, (size_t)N * 4, stream);

  k_prep<<<NBK + NWC + nGoff, 256, 0, stream>>>(
      srcp, dstp, cnt, bsrc, E, N, W_comb, gW1, gW2, Wcb, W1b, W2b, batch, goff, G,
      (unsigned int*)(Ub + (size_t)N * 128), (unsigned int*)(Vb + (size_t)N * 128));

  // u1 = W1[0] @ relu(Wc @ [emb||pe] + bc)
  k_init_mm<<<ntiles, 256, 0, stream>>>(z, pos, emb, W_pos, b_pos, Wcb, b_comb,
                                        W1b, Ub, N);

  // layer 0: u2
  k_layer<0><<<ntiles, 256, 0, stream>>>((const unsigned int*)Ub, cnt, bsrc, gb1,
                                         W2b, gb2, W1b + (size_t)1 * 128 * 128, Vb, N);
  // layer 1: u3
  k_layer<0><<<ntiles, 256, 0, stream>>>((const unsigned int*)Vb, cnt, bsrc, gb1 + 128,
                                         W2b + (size_t)1 * 128 * 128, gb2 + 128,
                                         W1b + (size_t)2 * 128 * 128, Ub, N);
  // layer 2: x3 (no relu, no W1next)
  k_layer<1><<<ntiles, 256, 0, stream>>>((const unsigned int*)Ub, cnt, bsrc, gb1 + 256,
                                         W2b + (size_t)2 * 128 * 128, gb2 + 256,
                                         (const unsigned short*)nullptr, Vb, N);

  k_pool<<<G, 256, 0, stream>>>(Vb, goff, Wp1, bp1, Wp2, bp2, out, G);
}